// Round 1
// baseline (2977.423 us; speedup 1.0000x reference)
//
#include <hip/hip_runtime.h>

// Problem constants
#define BB 16
#define TT 64
#define HH 256
#define NSUB 32              // blocks per batch
#define ROWS 8               // rows of M per block = HH / NSUB
#define NBLK (BB * NSUB)     // 512 blocks

// d_out layout (floats): hid[B][T][H], out[B][T][2], h_fin[B][H], new_j[B][H][H]
#define OUT_OFF  (BB * TT * HH)            // 262144
#define HFIN_OFF (OUT_OFF + BB * TT * 2)   // 264192
#define NJ_OFF   (HFIN_OFF + BB * HH)      // 268288

// beta * SIGMA_SYN * sqrt(beta) = 0.1 * 0.002 * sqrt(0.1)
#define C_SN    6.324555320336759e-05f
// PERT_SIGMA * sqrt(ALPHA) = 0.1 * 0.5
#define C_NOISE 0.05f

__global__ __launch_bounds__(256, 2) void rnn_all(
    const float* __restrict__ x,      // [B,T,2]
    const float* __restrict__ h0,     // [B,H]
    const float* __restrict__ w_in,   // [H,2]
    const float* __restrict__ w_hh,   // [H,H]
    const float* __restrict__ b_hh,   // [H]
    const float* __restrict__ w_out,  // [2,H]
    const float* __restrict__ nper,   // [B,H]
    const float* __restrict__ sn,     // [T,B,H,H]
    const int*   __restrict__ pt_ptr, // scalar
    float*       __restrict__ dout,
    unsigned int* __restrict__ cnt_base) // d_ws: 16 counters, 256B stride
{
    const int tid = threadIdx.x;          // column j
    const int bid = blockIdx.x;
    // bid = sub*16 + parity*8 + xcd  ->  all 32 blocks of a batch share bid%8
    // (heuristic XCD co-location; correctness does not depend on it)
    const int b   = 2 * (bid & 7) + ((bid >> 3) & 1);
    const int sub = bid >> 4;             // 0..31
    const int i0  = sub * ROWS;

    __shared__ float s_act[HH];
    __shared__ float s_red[8];

    unsigned int* cnt = cnt_base + b * 64;          // 256B stride per batch

    // djp scratch lives in this batch's new_j output region: [2][NSUB][HH] floats
    float* djp = dout + NJ_OFF + (size_t)b * (HH * HH);

    const int pt = *pt_ptr;

    // M[b][i][j] = w_hh[j][i]  (transposed w_hh; diff starts at 0)
    float M[ROWS];
    {
        const float4* wr = (const float4*)(w_hh + (size_t)tid * HH + i0);
        float4 a = wr[0], c = wr[1];
        M[0] = a.x; M[1] = a.y; M[2] = a.z; M[3] = a.w;
        M[4] = c.x; M[5] = c.y; M[6] = c.z; M[7] = c.w;
    }

    float h    = h0[b * HH + tid];
    float actj = tanhf(h);
    s_act[tid] = actj;

    const float win0 = w_in[tid * 2 + 0];
    const float win1 = w_in[tid * 2 + 1];
    const float bh   = b_hh[tid];
    const float npv  = nper[b * HH + tid] * C_NOISE;
    const float wo0  = w_out[tid];
    const float wo1  = w_out[HH + tid];

    // prefetch sn[t=0] rows for this block
    float sreg[ROWS];
    {
        const float* snp = sn + ((size_t)b * HH + i0) * HH + tid;
        #pragma unroll
        for (int r = 0; r < ROWS; ++r) sreg[r] = snp[(size_t)r * HH];
    }
    __syncthreads();

    for (int t = 0; t < TT; ++t) {
        // ---- phase A: partial matvec with pre-update M; apply anti-Hebbian update
        float partial = 0.f;
        #pragma unroll
        for (int r = 0; r < ROWS; ++r) {
            const float ai = s_act[i0 + r];
            partial += ai * M[r];
            M[r] -= 0.1f * ai * actj;      // beta * outer(act,act)
        }
        djp[((t & 1) * NSUB + sub) * HH + tid] = partial;
        __syncthreads();                    // all djp stores of this block drained

        // ---- per-batch barrier (monotonic counter, release/acquire)
        if (tid == 0) {
            __threadfence();                // publish djp beyond L2
            atomicAdd(cnt, 1u);
            const unsigned tgt = (unsigned)(NSUB * (t + 1));
            while (__hip_atomic_load(cnt, __ATOMIC_RELAXED, __HIP_MEMORY_SCOPE_AGENT) < tgt)
                __builtin_amdgcn_s_sleep(4);
        }
        __syncthreads();
        __threadfence();                    // acquire: invalidate stale L1/L2 for djp reads

        // ---- phase B (redundant across the batch's 32 blocks; bitwise identical)
        float dj = 0.f;
        {
            const float* src = djp + (t & 1) * (NSUB * HH) + tid;
            #pragma unroll
            for (int s = 0; s < NSUB; ++s) dj += src[s * HH];
        }

        // consume sn[t] (loaded long ago), then prefetch sn[t+1]
        #pragma unroll
        for (int r = 0; r < ROWS; ++r) M[r] += C_SN * sreg[r];
        if (t + 1 < TT) {
            const float* snp = sn + (((size_t)(t + 1) * BB + b) * HH + i0) * HH + tid;
            #pragma unroll
            for (int r = 0; r < ROWS; ++r) sreg[r] = snp[(size_t)r * HH];
        }

        const float x0 = x[(b * TT + t) * 2 + 0];
        const float x1 = x[(b * TT + t) * 2 + 1];
        const float tmp = x0 * win0 + x1 * win1 + bh + dj;
        h = 0.75f * h + 0.25f * tmp + ((t == pt) ? npv : 0.f);
        actj = tanhf(h);
        s_act[tid] = actj;                  // for next step's phase A

        // ---- outputs (split across sub-blocks to balance)
        if (sub == 0) {
            dout[((size_t)b * TT + t) * HH + tid] = h;
        } else if (sub == 1) {
            float p0 = h * wo0, p1 = h * wo1;
            #pragma unroll
            for (int off = 32; off > 0; off >>= 1) {
                p0 += __shfl_down(p0, off, 64);
                p1 += __shfl_down(p1, off, 64);
            }
            const int wv = tid >> 6, ln = tid & 63;
            if (ln == 0) { s_red[wv] = p0; s_red[4 + wv] = p1; }
            __syncthreads();
            if (tid == 0) {
                dout[OUT_OFF + (b * TT + t) * 2 + 0] = s_red[0] + s_red[1] + s_red[2] + s_red[3];
                dout[OUT_OFF + (b * TT + t) * 2 + 1] = s_red[4] + s_red[5] + s_red[6] + s_red[7];
            }
        } else if (sub == 2 && t == TT - 1) {
            dout[HFIN_OFF + b * HH + tid] = h;
        }
        __syncthreads();                    // s_act visible for next iteration
    }

    // ---- final per-batch barrier: everyone finished reading djp scratch
    if (tid == 0) {
        __threadfence();
        atomicAdd(cnt, 1u);
        const unsigned tgt = (unsigned)(NSUB * (TT + 1));
        while (__hip_atomic_load(cnt, __ATOMIC_RELAXED, __HIP_MEMORY_SCOPE_AGENT) < tgt)
            __builtin_amdgcn_s_sleep(4);
    }
    __syncthreads();

    // ---- write new_j = w_hh (broadcast) + diff = w_hh[i][j] + M - w_hh[j][i]
    #pragma unroll
    for (int r = 0; r < ROWS; ++r) {
        const int i = i0 + r;
        dout[NJ_OFF + ((size_t)b * HH + i) * HH + tid] =
            w_hh[(size_t)i * HH + tid] + M[r] - w_hh[(size_t)tid * HH + i];
    }
}

extern "C" void kernel_launch(void* const* d_in, const int* in_sizes, int n_in,
                              void* d_out, int out_size, void* d_ws, size_t ws_size,
                              hipStream_t stream) {
    (void)in_sizes; (void)n_in; (void)out_size; (void)ws_size;
    const float* x     = (const float*)d_in[0];
    const float* h0    = (const float*)d_in[1];
    const float* w_in  = (const float*)d_in[2];
    const float* w_hh  = (const float*)d_in[3];
    const float* b_hh  = (const float*)d_in[4];
    const float* w_out = (const float*)d_in[5];
    const float* nper  = (const float*)d_in[6];
    const float* sn    = (const float*)d_in[7];
    const int*   pt    = (const int*)d_in[8];
    float* dout        = (float*)d_out;
    unsigned int* cnt  = (unsigned int*)d_ws;

    // per-launch reset of barrier counters (16 batches x 256B stride)
    hipMemsetAsync(d_ws, 0, 16 * 64 * sizeof(unsigned int), stream);

    void* args[] = { &x, &h0, &w_in, &w_hh, &b_hh, &w_out, &nper, &sn, &pt, &dout, &cnt };
    hipLaunchCooperativeKernel((void*)rnn_all, dim3(NBLK), dim3(256), args, 0, stream);
}

// Round 4
// 200.707 us; speedup vs baseline: 14.8347x; 14.8347x over previous
//
#include <hip/hip_runtime.h>

// Problem constants
#define BB 16
#define TT 64
#define HH 256
#define NSUB 4               // blocks per batch
#define ROWS 64              // rows of M per block = HH / NSUB
#define NBLK (BB * NSUB)     // 64 blocks

// d_out layout (floats): hid[B][T][H], out[B][T][2], h_fin[B][H], new_j[B][H][H]
#define OUT_OFF  (BB * TT * HH)            // 262144
#define HFIN_OFF (OUT_OFF + BB * TT * 2)   // 264192
#define NJ_OFF   (HFIN_OFF + BB * HH)      // 268288

// beta * SIGMA_SYN * sqrt(beta) = 0.1 * 0.002 * sqrt(0.1)
#define C_SN    6.324555320336759e-05f
// PERT_SIGMA * sqrt(ALPHA) = 0.1 * 0.5
#define C_NOISE 0.05f

typedef unsigned long long u64;
typedef unsigned int u32;

// RMW-based communication: atomic RMWs execute at the device coherence point
// (memory side), so they can neither be stale-read nor lost in a local cache
// (round-1/2 counters proved RMW progress cross-XCD; round-2 proved relaxed
// plain atomics CAN be stale). The step tag travels WITH the data in one
// 8-byte packet -> no ordering requirements, no fences, no cache-wide ops.
__device__ __forceinline__ void slot_put(u64* p, u64 v) {
    (void)__hip_atomic_exchange(p, v, __ATOMIC_RELAXED, __HIP_MEMORY_SCOPE_AGENT);
}
__device__ __forceinline__ u64 slot_get(u64* p) {
    return __hip_atomic_fetch_add(p, 0ull, __ATOMIC_RELAXED, __HIP_MEMORY_SCOPE_AGENT);
}

__global__ __launch_bounds__(256, 1) void rnn_all(
    const float* __restrict__ x,      // [B,T,2]
    const float* __restrict__ h0,     // [B,H]
    const float* __restrict__ w_in,   // [H,2]
    const float* __restrict__ w_hh,   // [H,H]
    const float* __restrict__ b_hh,   // [H]
    const float* __restrict__ w_out,  // [2,H]
    const float* __restrict__ nper,   // [B,H]
    const float* __restrict__ sn,     // [T,B,H,H]
    const int*   __restrict__ pt_ptr, // scalar
    float*       __restrict__ dout,
    u32*         __restrict__ cnt_base) // d_ws: 16 counters, 256B stride
{
    const int tid = threadIdx.x;          // column j
    const int bid = blockIdx.x;
    const int b   = bid >> 2;             // batch
    const int sub = bid & (NSUB - 1);     // 0..3
    const int i0  = sub * ROWS;

    __shared__ float s_act[2][HH];
    __shared__ float s_red[8];

    u32* cnt = cnt_base + b * 64;         // 256B stride per batch

    // slot scratch [2][NSUB][HH] u64 lives at the start of batch b's new_j
    // output region (16 KB of the 256 KB quarter); memset to 0 each launch.
    u64* djp = (u64*)(dout + NJ_OFF + (size_t)b * (HH * HH));

    const int pt = *pt_ptr;

    // M[i][j] = w_hh[j][i] + diff[i][j]; starts as transposed w_hh (diff = 0)
    float M[ROWS];
    {
        const float4* wr = (const float4*)(w_hh + (size_t)tid * HH + i0);
        #pragma unroll
        for (int q = 0; q < ROWS / 4; ++q) {
            float4 a = wr[q];
            M[4*q+0] = a.x; M[4*q+1] = a.y; M[4*q+2] = a.z; M[4*q+3] = a.w;
        }
    }

    float h    = h0[b * HH + tid];
    float actj = tanhf(h);
    s_act[0][tid] = actj;

    const float win0 = w_in[tid * 2 + 0];
    const float win1 = w_in[tid * 2 + 1];
    const float bh   = b_hh[tid];
    const float npv  = nper[b * HH + tid] * C_NOISE;
    const float wo0  = w_out[tid];
    const float wo1  = w_out[HH + tid];

    // prefetch sn[t=0] rows for this block
    float sreg[ROWS];
    {
        const float* snp = sn + ((size_t)b * HH + i0) * HH + tid;
        #pragma unroll
        for (int r = 0; r < ROWS; ++r) sreg[r] = snp[(size_t)r * HH];
    }
    __syncthreads();

    for (int t = 0; t < TT; ++t) {
        const int cur = t & 1, nxt = cur ^ 1;
        const u32 tagw = (u32)(t + 1);

        // ---- phase A: partial matvec with pre-update M, publish IMMEDIATELY
        float partial = 0.f;
        #pragma unroll
        for (int r = 0; r < ROWS; ++r) partial += s_act[cur][i0 + r] * M[r];

        slot_put(djp + cur * (NSUB * HH) + sub * HH + tid,
                 ((u64)tagw << 32) | (u64)__float_as_uint(partial));

        // ---- poll-shadow work: x loads, M update (outer + sn), sn prefetch
        const float x0 = x[(b * TT + t) * 2 + 0];
        const float x1 = x[(b * TT + t) * 2 + 1];

        #pragma unroll
        for (int r = 0; r < ROWS; ++r)
            M[r] += C_SN * sreg[r] - 0.1f * s_act[cur][i0 + r] * actj;

        if (t + 1 < TT) {
            const float* snp = sn + (((size_t)(t + 1) * BB + b) * HH + i0) * HH + tid;
            #pragma unroll
            for (int r = 0; r < ROWS; ++r) sreg[r] = snp[(size_t)r * HH];
        }

        // ---- poll the 4 packets for column tid (RMW reads: never stale)
        u64 v0, v1, v2, v3;
        {
            u64* base = djp + cur * (NSUB * HH) + tid;
            for (;;) {
                v0 = slot_get(base + 0 * HH);
                v1 = slot_get(base + 1 * HH);
                v2 = slot_get(base + 2 * HH);
                v3 = slot_get(base + 3 * HH);
                bool ok = ((u32)(v0 >> 32) == tagw) & ((u32)(v1 >> 32) == tagw)
                        & ((u32)(v2 >> 32) == tagw) & ((u32)(v3 >> 32) == tagw);
                if (ok) break;
            }
        }
        const float dj = __uint_as_float((u32)v0) + __uint_as_float((u32)v1)
                       + __uint_as_float((u32)v2) + __uint_as_float((u32)v3);

        // ---- h update (redundant per block; bitwise identical)
        const float tmp = x0 * win0 + x1 * win1 + bh + dj;
        h = 0.75f * h + 0.25f * tmp + ((t == pt) ? npv : 0.f);
        actj = tanhf(h);
        s_act[nxt][tid] = actj;

        // ---- outputs (split across sub-blocks)
        if (sub == 0) {
            dout[((size_t)b * TT + t) * HH + tid] = h;
        } else if (sub == 1) {
            float p0 = h * wo0, p1 = h * wo1;
            #pragma unroll
            for (int off = 32; off > 0; off >>= 1) {
                p0 += __shfl_down(p0, off, 64);
                p1 += __shfl_down(p1, off, 64);
            }
            const int wv = tid >> 6, ln = tid & 63;
            if (ln == 0) { s_red[wv] = p0; s_red[4 + wv] = p1; }
            __syncthreads();               // block-uniform branch: legal
            if (tid == 0) {
                dout[OUT_OFF + (b * TT + t) * 2 + 0] = s_red[0] + s_red[1] + s_red[2] + s_red[3];
                dout[OUT_OFF + (b * TT + t) * 2 + 1] = s_red[4] + s_red[5] + s_red[6] + s_red[7];
            }
        } else if (sub == 2 && t == TT - 1) {
            dout[HFIN_OFF + b * HH + tid] = h;
        }
        __syncthreads();                   // s_act[nxt] ready for next step
    }

    // ---- final per-batch arrival barrier (RMW counter): all blocks done
    // reading the djp slots before we overwrite the region with new_j.
    if (tid == 0) {
        (void)__hip_atomic_fetch_add(cnt, 1u, __ATOMIC_RELAXED, __HIP_MEMORY_SCOPE_AGENT);
        while (__hip_atomic_fetch_add(cnt, 0u, __ATOMIC_RELAXED, __HIP_MEMORY_SCOPE_AGENT)
               < (u32)NSUB)
            __builtin_amdgcn_s_sleep(2);
    }
    __syncthreads();

    // ---- write new_j[b][i][j] = w_hh[i][j] + (M[i][j] - w_hh[j][i])
    #pragma unroll
    for (int r = 0; r < ROWS; ++r) {
        const int i = i0 + r;
        dout[NJ_OFF + ((size_t)b * HH + i) * HH + tid] =
            w_hh[(size_t)i * HH + tid] + M[r] - w_hh[(size_t)tid * HH + i];
    }
}

extern "C" void kernel_launch(void* const* d_in, const int* in_sizes, int n_in,
                              void* d_out, int out_size, void* d_ws, size_t ws_size,
                              hipStream_t stream) {
    (void)in_sizes; (void)n_in; (void)out_size; (void)ws_size;
    const float* x     = (const float*)d_in[0];
    const float* h0    = (const float*)d_in[1];
    const float* w_in  = (const float*)d_in[2];
    const float* w_hh  = (const float*)d_in[3];
    const float* b_hh  = (const float*)d_in[4];
    const float* w_out = (const float*)d_in[5];
    const float* nper  = (const float*)d_in[6];
    const float* sn    = (const float*)d_in[7];
    const int*   pt    = (const int*)d_in[8];
    float* dout        = (float*)d_out;
    u32* cnt           = (u32*)d_ws;

    // reset barrier counters and the tagged-slot scratch (tags -> 0) each
    // launch so graph replays are deterministic (d_ws/d_out are poisoned
    // to 0xAA before timing -- tags MUST be re-zeroed here).
    hipMemsetAsync(d_ws, 0, 16 * 64 * sizeof(u32), stream);
    hipMemsetAsync((void*)(dout + NJ_OFF), 0, (size_t)BB * HH * HH * sizeof(float), stream);

    // PLAIN launch: 64 blocks on a 256-CU idle GPU are trivially co-resident
    // (the only requirement of the homegrown barrier). Round 3's identical
    // body never ran -- suspect hipLaunchCooperativeKernel validation; this
    // removes that path.
    rnn_all<<<dim3(NBLK), dim3(256), 0, stream>>>(
        x, h0, w_in, w_hh, b_hh, w_out, nper, sn, pt, dout, cnt);
}

// Round 5
// 180.939 us; speedup vs baseline: 16.4554x; 1.1093x over previous
//
#include <hip/hip_runtime.h>

// Problem constants
#define BB 16
#define TT 64
#define HH 256
#define NSUB 16              // blocks per batch (sub 0 = aggregator)
#define ROWS 16              // rows of M per block = HH / NSUB
#define NBLK (BB * NSUB)     // 256 blocks

// d_out layout (floats): hid[B][T][H], out[B][T][2], h_fin[B][H], new_j[B][H][H]
#define OUT_OFF  (BB * TT * HH)            // 262144
#define HFIN_OFF (OUT_OFF + BB * TT * 2)   // 264192
#define NJ_OFF   (HFIN_OFF + BB * HH)      // 268288

// beta * SIGMA_SYN * sqrt(beta) = 0.1 * 0.002 * sqrt(0.1)
#define C_SN    6.324555320336759e-05f
// PERT_SIGMA * sqrt(ALPHA) = 0.1 * 0.5
#define C_NOISE 0.05f

typedef unsigned long long u64;
typedef unsigned int u32;

// RMW-based cross-XCD communication (proven rounds 3/4): atomic RMWs execute
// at the device coherence point; publisher uses exchange (pushes data out of
// the local XCD), consumer uses fetch_add(0) (cannot read stale). The step
// tag travels WITH the data in one 8B packet -> no fences, no ordering deps.
__device__ __forceinline__ void slot_put(u64* p, u64 v) {
    (void)__hip_atomic_exchange(p, v, __ATOMIC_RELAXED, __HIP_MEMORY_SCOPE_AGENT);
}
__device__ __forceinline__ u64 slot_get(u64* p) {
    return __hip_atomic_fetch_add(p, 0ull, __ATOMIC_RELAXED, __HIP_MEMORY_SCOPE_AGENT);
}
__device__ __forceinline__ u64 pack(u32 tag, float v) {
    return ((u64)tag << 32) | (u64)__float_as_uint(v);
}

__global__ __launch_bounds__(256) void rnn_all(
    const float* __restrict__ x,      // [B,T,2]
    const float* __restrict__ h0,     // [B,H]
    const float* __restrict__ w_in,   // [H,2]
    const float* __restrict__ w_hh,   // [H,H]
    const float* __restrict__ b_hh,   // [H]
    const float* __restrict__ w_out,  // [2,H]
    const float* __restrict__ nper,   // [B,H]
    const float* __restrict__ sn,     // [T,B,H,H]
    const int*   __restrict__ pt_ptr, // scalar
    float*       __restrict__ dout,
    u32*         __restrict__ cnt_base) // d_ws: 16 counters, 256B stride
{
    const int tid = threadIdx.x;          // column j
    const int bid = blockIdx.x;
    const int b   = bid >> 4;             // batch
    const int sub = bid & (NSUB - 1);     // 0..15
    const int i0  = sub * ROWS;
    const bool isagg = (sub == 0);

    __shared__ float s_act[2][HH];
    __shared__ float s_red[8];
    __shared__ float s_x[2 * TT];

    u32* cnt = cnt_base + b * 64;         // 256B stride per batch

    // packet regions inside batch b's new_j output area (memset to 0 / launch):
    //   partial slots [2][NSUB][HH] u64 = 64 KB, act slots [2][HH] u64 = 4 KB
    u64* slotbase = (u64*)(dout + NJ_OFF + (size_t)b * (HH * HH));
    u64* actbase  = slotbase + 2 * NSUB * HH;

    const int pt = *pt_ptr;

    // M[i][j] = w_hh[j][i] + diff[i][j]; starts as transposed w_hh (diff = 0)
    float M[ROWS];
    {
        const float4* wr = (const float4*)(w_hh + (size_t)tid * HH + i0);
        #pragma unroll
        for (int q = 0; q < ROWS / 4; ++q) {
            float4 a = wr[q];
            M[4*q+0] = a.x; M[4*q+1] = a.y; M[4*q+2] = a.z; M[4*q+3] = a.w;
        }
    }

    float h    = h0[b * HH + tid];
    float actj = tanhf(h);
    s_act[0][tid] = actj;
    if (tid < 2 * TT) s_x[tid] = x[b * 2 * TT + tid];

    const float win0 = w_in[tid * 2 + 0];
    const float win1 = w_in[tid * 2 + 1];
    const float bh   = b_hh[tid];
    const float npv  = nper[b * HH + tid] * C_NOISE;
    const float wo0  = w_out[tid];
    const float wo1  = w_out[HH + tid];

    // prefetch sn[t=0] rows for this block
    float sreg[ROWS];
    {
        const float* snp = sn + ((size_t)b * HH + i0) * HH + tid;
        #pragma unroll
        for (int r = 0; r < ROWS; ++r) sreg[r] = snp[(size_t)r * HH];
    }
    __syncthreads();

    for (int t = 0; t < TT; ++t) {
        const int cur = t & 1, nxt = cur ^ 1;
        const u32 tagw = (u32)(t + 1);

        // ---- partial matvec with pre-update M (act of time t)
        float partial = 0.f;
        #pragma unroll
        for (int r = 0; r < ROWS; ++r) partial += s_act[cur][i0 + r] * M[r];

        if (!isagg)
            slot_put(slotbase + (cur * NSUB + sub) * HH + tid, pack(tagw, partial));

        // ---- shadow work: M outer+sn update, sn[t+1] prefetch
        #pragma unroll
        for (int r = 0; r < ROWS; ++r)
            M[r] += C_SN * sreg[r] - 0.1f * s_act[cur][i0 + r] * actj;

        if (t + 1 < TT) {
            const float* snp = sn + (((size_t)(t + 1) * BB + b) * HH + i0) * HH + tid;
            #pragma unroll
            for (int r = 0; r < ROWS; ++r) sreg[r] = snp[(size_t)r * HH];
        }

        if (isagg) {
            // ---- poll the 15 partial packets for column tid
            u64 vv[NSUB - 1];
            for (;;) {
                bool ok = true;
                #pragma unroll
                for (int s = 1; s < NSUB; ++s) {
                    vv[s-1] = slot_get(slotbase + (cur * NSUB + s) * HH + tid);
                    ok &= ((u32)(vv[s-1] >> 32) == tagw);
                }
                if (ok) break;
            }
            float dj = partial;
            #pragma unroll
            for (int s = 1; s < NSUB; ++s) dj += __uint_as_float((u32)vv[s-1]);

            // ---- h update (computed ONCE per batch)
            const float tmp = s_x[2*t] * win0 + s_x[2*t+1] * win1 + bh + dj;
            h = 0.75f * h + 0.25f * tmp + ((t == pt) ? npv : 0.f);
            actj = tanhf(h);
            // broadcast act FIRST (critical path), outputs after
            slot_put(actbase + cur * HH + tid, pack(tagw, actj));
            s_act[nxt][tid] = actj;

            // ---- outputs (in the shadow of subs' round trip)
            dout[((size_t)b * TT + t) * HH + tid] = h;
            float p0 = h * wo0, p1 = h * wo1;
            #pragma unroll
            for (int off = 32; off > 0; off >>= 1) {
                p0 += __shfl_down(p0, off, 64);
                p1 += __shfl_down(p1, off, 64);
            }
            const int wv = tid >> 6, ln = tid & 63;
            if (ln == 0) { s_red[wv] = p0; s_red[4 + wv] = p1; }
            __syncthreads();               // block-uniform branch: legal
            if (tid == 0) {
                dout[OUT_OFF + (b * TT + t) * 2 + 0] = s_red[0] + s_red[1] + s_red[2] + s_red[3];
                dout[OUT_OFF + (b * TT + t) * 2 + 1] = s_red[4] + s_red[5] + s_red[6] + s_red[7];
            }
            if (t == TT - 1) dout[HFIN_OFF + b * HH + tid] = h;
        } else {
            // ---- poll the single act packet for column tid
            u64 av;
            do { av = slot_get(actbase + cur * HH + tid); }
            while ((u32)(av >> 32) != tagw);
            actj = __uint_as_float((u32)av);
            s_act[nxt][tid] = actj;
        }
        __syncthreads();                   // s_act[nxt] ready for next step
    }

    // ---- final per-batch arrival barrier (RMW counter): all blocks done
    // reading the packet slots before we overwrite the region with new_j.
    if (tid == 0) {
        (void)__hip_atomic_fetch_add(cnt, 1u, __ATOMIC_RELAXED, __HIP_MEMORY_SCOPE_AGENT);
        while (__hip_atomic_fetch_add(cnt, 0u, __ATOMIC_RELAXED, __HIP_MEMORY_SCOPE_AGENT)
               < (u32)NSUB)
            __builtin_amdgcn_s_sleep(2);
    }
    __syncthreads();

    // ---- write new_j[b][i][j] = w_hh[i][j] + (M[i][j] - w_hh[j][i])
    #pragma unroll
    for (int r = 0; r < ROWS; ++r) {
        const int i = i0 + r;
        dout[NJ_OFF + ((size_t)b * HH + i) * HH + tid] =
            w_hh[(size_t)i * HH + tid] + M[r] - w_hh[(size_t)tid * HH + i];
    }
}

extern "C" void kernel_launch(void* const* d_in, const int* in_sizes, int n_in,
                              void* d_out, int out_size, void* d_ws, size_t ws_size,
                              hipStream_t stream) {
    (void)in_sizes; (void)n_in; (void)out_size; (void)ws_size;
    const float* x     = (const float*)d_in[0];
    const float* h0    = (const float*)d_in[1];
    const float* w_in  = (const float*)d_in[2];
    const float* w_hh  = (const float*)d_in[3];
    const float* b_hh  = (const float*)d_in[4];
    const float* w_out = (const float*)d_in[5];
    const float* nper  = (const float*)d_in[6];
    const float* sn    = (const float*)d_in[7];
    const int*   pt    = (const int*)d_in[8];
    float* dout        = (float*)d_out;
    u32* cnt           = (u32*)d_ws;

    // reset barrier counters and the tagged-slot scratch (tags -> 0) each
    // launch so graph replays are deterministic (buffers are poisoned 0xAA).
    hipMemsetAsync(d_ws, 0, 16 * 64 * sizeof(u32), stream);
    hipMemsetAsync((void*)(dout + NJ_OFF), 0, (size_t)BB * HH * HH * sizeof(float), stream);

    rnn_all<<<dim3(NBLK), dim3(256), 0, stream>>>(
        x, h0, w_in, w_hh, b_hh, w_out, nper, sn, pt, dout, cnt);
}